// Round 1
// baseline (267.321 us; speedup 1.0000x reference)
//
#include <hip/hip_runtime.h>

#define L_IN   4000
#define CIN    512
#define KSZ    16
#define LOUT   31992   // 8 * 3999
#define NQ     3999    // valid q: 0..3998
#define QTILE  64

// Each block: one (b, q-tile of 64). 4 waves split Cin into 128-chunks.
// Thread = one q position, 8 output accumulators (r = 0..7).
// Weights are wave-uniform -> scalar loads (s_load), no LDS broadcast cost.
__global__ __launch_bounds__(256, 4)
void dereverb_kernel(const float* __restrict__ x,
                     const float* __restrict__ t60s,
                     const float* __restrict__ kw,
                     float* __restrict__ out)
{
    const int b    = blockIdx.y;
    const int q0   = blockIdx.x * QTILE;
    const int tid  = threadIdx.x;
    const int lane = tid & 63;
    const int wave = tid >> 6;

    // Per-sample kernel index: idx[b] = rint(t60s[b % 8] * 100) - 10 (uniform).
    // jnp.round is round-half-even -> rintf (default RNE) matches.
    float t60 = t60s[b & 7];
    int kidx = (int)rintf(t60 * 100.0f) - 10;
    kidx = __builtin_amdgcn_readfirstlane(kidx);   // force SGPR -> scalar weight loads
    const float* wbase = kw + (size_t)kidx * (CIN * KSZ);

    const int q  = q0 + lane;
    const int qc = q < (NQ - 1) ? q : (NQ - 1);    // clamp so loads stay in-bounds

    const int cw = wave * 128;                     // this wave's Cin chunk
    const float* xp = x + ((size_t)b * CIN + cw) * L_IN + qc;
    const float* wp = wbase + cw * KSZ;

    float acc[8];
    #pragma unroll
    for (int r = 0; r < 8; ++r) acc[r] = 0.0f;

    #pragma unroll 4
    for (int i = 0; i < 128; ++i) {
        float x0 = xp[0];        // x[b, ci, q]
        float x1 = xp[1];        // x[b, ci, q+1]  (always in-bounds: qc+1 <= 3999)
        #pragma unroll
        for (int r = 0; r < 8; ++r) {
            acc[r] = fmaf(x1, wp[r],     acc[r]);
            acc[r] = fmaf(x0, wp[r + 8], acc[r]);
        }
        xp += L_IN;
        wp += KSZ;
    }

    if (q > NQ - 1) {            // clamped lanes contribute nothing
        #pragma unroll
        for (int r = 0; r < 8; ++r) acc[r] = 0.0f;
    }

    // Cross-wave reduction: red[wave][r*64 + lane] (r-major: conflict-free stores)
    __shared__ float red[4 * 512];
    #pragma unroll
    for (int r = 0; r < 8; ++r)
        red[wave * 512 + r * 64 + lane] = acc[r];
    __syncthreads();

    // Each thread produces 2 consecutive outputs j = 2*tid, 2*tid+1
    // output t = 8*q0 + j;  j = 8*(q-q0) + r  ->  LDS addr (j&7)*64 + (j>>3)
    const int base_t = q0 * 8;
    const int j0 = tid * 2;
    if (base_t + j0 < LOUT) {    // cutoff is even -> pair never straddles
        float s0 = 0.0f, s1 = 0.0f;
        #pragma unroll
        for (int w = 0; w < 4; ++w) {
            s0 += red[w * 512 + ((j0)     & 7) * 64 + ((j0)     >> 3)];
            s1 += red[w * 512 + ((j0 + 1) & 7) * 64 + ((j0 + 1) >> 3)];
        }
        *(float2*)(out + (size_t)b * LOUT + base_t + j0) = make_float2(s0, s1);
    }
}

extern "C" void kernel_launch(void* const* d_in, const int* in_sizes, int n_in,
                              void* d_out, int out_size, void* d_ws, size_t ws_size,
                              hipStream_t stream) {
    const float* x    = (const float*)d_in[0];   // (16, 512, 4000)
    const float* t60s = (const float*)d_in[1];   // (8,)
    const float* kw   = (const float*)d_in[2];   // (41, 512, 1, 16)
    float* out = (float*)d_out;                  // (16, 1, 31992)

    dim3 grid((NQ + QTILE - 1) / QTILE, 16);     // (63, 16)
    dereverb_kernel<<<grid, 256, 0, stream>>>(x, t60s, kw, out);
}

// Round 2
// 190.425 us; speedup vs baseline: 1.4038x; 1.4038x over previous
//
#include <hip/hip_runtime.h>

#define L_IN   4000
#define CIN    512
#define KSZ    16
#define LOUT   31992   // 8 * 3999
#define NQ     3999    // valid q: 0..3998
#define QTILE  64

// Block = (b, q-tile of 64). 4 waves split Cin into 128-ci chunks.
// Thread = one q position, 8 output accumulators (r = 0..7).
// Weights staged once into LDS; inner loop reads them via wave-uniform
// ds_read_b128 (broadcast, conflict-free). LDS reused for the reduction.
__global__ __launch_bounds__(256, 4)
void dereverb_kernel(const float* __restrict__ x,
                     const float* __restrict__ t60s,
                     const float* __restrict__ kw,
                     float* __restrict__ out)
{
    __shared__ float lds[CIN * KSZ];   // 32 KB: weights, later reused for reduction

    const int b    = blockIdx.y;
    const int q0   = blockIdx.x * QTILE;
    const int tid  = threadIdx.x;
    const int lane = tid & 63;
    const int wave = tid >> 6;

    // Per-sample kernel index (uniform): jnp.round = RNE = rintf.
    float t60 = t60s[b & 7];
    int kidx = (int)rintf(t60 * 100.0f) - 10;
    kidx = __builtin_amdgcn_readfirstlane(kidx);
    const float4* wsrc = (const float4*)(kw + (size_t)kidx * (CIN * KSZ));

    // Stage all 512x16 weights: 2048 float4, 8 per thread, coalesced.
    #pragma unroll
    for (int i = 0; i < 8; ++i)
        ((float4*)lds)[tid + i * 256] = wsrc[tid + i * 256];
    __syncthreads();

    const int q  = q0 + lane;
    const int qc = q < (NQ - 1) ? q : (NQ - 1);   // clamp: loads stay in-bounds

    const int cw = wave * 128;                    // this wave's Cin chunk
    const float*  xp = x + ((size_t)b * CIN + cw) * L_IN + qc;
    const float4* wl = (const float4*)(lds + cw * KSZ);

    float acc[8];
    #pragma unroll
    for (int r = 0; r < 8; ++r) acc[r] = 0.0f;

    #pragma unroll 8
    for (int i = 0; i < 128; ++i) {
        float x0 = xp[0];        // x[b, ci, q]
        float x1 = xp[1];        // x[b, ci, q+1]  (qc+1 <= 3999, in-bounds)
        float4 wv[4];
        wv[0] = wl[0];           // ds_read_b128, wave-uniform addr -> broadcast
        wv[1] = wl[1];
        wv[2] = wl[2];
        wv[3] = wl[3];
        const float* wf = (const float*)wv;   // constant-indexed after unroll
        #pragma unroll
        for (int r = 0; r < 8; ++r) {
            acc[r] = fmaf(x1, wf[r],     acc[r]);
            acc[r] = fmaf(x0, wf[r + 8], acc[r]);
        }
        xp += L_IN;
        wl += 4;
    }

    if (q > NQ - 1) {            // clamped lanes contribute nothing
        #pragma unroll
        for (int r = 0; r < 8; ++r) acc[r] = 0.0f;
    }

    // Reuse weight LDS for cross-wave reduction (all weight reads are done).
    __syncthreads();
    float* red = lds;            // layout: red[wave*520 + r*65 + lane], padded
    #pragma unroll
    for (int r = 0; r < 8; ++r)
        red[wave * 520 + r * 65 + lane] = acc[r];
    __syncthreads();

    // Thread writes 2 consecutive outputs j = 2*tid, 2*tid+1.
    // t = 8*q0 + j;  j = 8*(q-q0) + r  ->  LDS addr r*65 + (q-q0)
    const int base_t = q0 * 8;
    const int j0 = tid * 2;
    if (base_t + j0 < LOUT) {    // cutoff is even -> pair never straddles
        float s0 = 0.0f, s1 = 0.0f;
        #pragma unroll
        for (int w = 0; w < 4; ++w) {
            s0 += red[w * 520 + ((j0)     & 7) * 65 + ((j0)     >> 3)];
            s1 += red[w * 520 + ((j0 + 1) & 7) * 65 + ((j0 + 1) >> 3)];
        }
        *(float2*)(out + (size_t)b * LOUT + base_t + j0) = make_float2(s0, s1);
    }
}

extern "C" void kernel_launch(void* const* d_in, const int* in_sizes, int n_in,
                              void* d_out, int out_size, void* d_ws, size_t ws_size,
                              hipStream_t stream) {
    const float* x    = (const float*)d_in[0];   // (16, 512, 4000)
    const float* t60s = (const float*)d_in[1];   // (8,)
    const float* kw   = (const float*)d_in[2];   // (41, 512, 1, 16)
    float* out = (float*)d_out;                  // (16, 1, 31992)

    dim3 grid((NQ + QTILE - 1) / QTILE, 16);     // (63, 16)
    dereverb_kernel<<<grid, 256, 0, stream>>>(x, t60s, kw, out);
}